// Round 14
// baseline (582.568 us; speedup 1.0000x reference)
//
#include <hip/hip_runtime.h>

#define NQv   32768
#define TOTW  78336
#define OW00  0
#define OW01  18432
#define OW02  27648
#define OW10  36864
#define OW11  55296
#define OW12  64512
#define OWPOST 73728
#define ASTR  104     // act plane stride in shorts (208B = 13*16B)

typedef __attribute__((ext_vector_type(8))) short  short8;
typedef __attribute__((ext_vector_type(4))) float  float4v;

__device__ __forceinline__ float bfu2f(unsigned short u) {
  return __uint_as_float(((unsigned int)u) << 16);
}
__device__ __forceinline__ unsigned short f2bfu(float f) {
  unsigned int x = __float_as_uint(f);
  x += 0x7fffu + ((x >> 16) & 1u);   // RNE
  return (unsigned short)(x >> 16);
}
// ties-away bf16 round, result in bits [31:16]
__device__ __forceinline__ unsigned int rnd16(float f) {
  return __float_as_uint(f) + 0x8000u;
}
// pack two floats -> (bf16(hi)<<16)|bf16(lo) in 3 VALU
__device__ __forceinline__ unsigned int pkp(float lo, float hi) {
  return __builtin_amdgcn_perm(rnd16(hi), rnd16(lo), 0x07060302u);
}
__device__ __forceinline__ float silu_f(float x) { return x / (1.f + __expf(-x)); }
__device__ __forceinline__ int clamp31(int v) { return min(max(v, 0), 31); }

// ---- pre-kernel 1: weights -> bf16 hi/lo [n][kpad] + centered-coord bias adjust ----
__global__ __launch_bounds__(256) void convert_weights(
    const float* __restrict__ w00, const float* __restrict__ w01,
    const float* __restrict__ w02, const float* __restrict__ w10,
    const float* __restrict__ w11, const float* __restrict__ w12,
    const float* __restrict__ wpost,
    const float* __restrict__ b00, const float* __restrict__ b10,
    unsigned short* __restrict__ ws)
{
  int e = blockIdx.x * 256 + threadIdx.x;
  if (e >= TOTW + 192) return;
  if (e >= TOTW) {
    int e2 = e - TOTW, mat = e2 / 96, ch = e2 - mat * 96;
    const float* w = mat ? w10 : w00;
    const float* bb = mat ? b10 : b00;
    float s = bb[ch];
#pragma unroll
    for (int k = 0; k < 6; ++k) s += 15.5f * w[(96 + k) * 96 + ch];
    ((float*)(ws + 2 * TOTW))[e2] = s;
    return;
  }
  int base, kpad, Ksrc, Nsrc; const float* src;
  if      (e < OW01)  { base = OW00;  kpad = 192; Ksrc = 174; Nsrc = 96; src = w00; }
  else if (e < OW02)  { base = OW01;  kpad = 96;  Ksrc = 96;  Nsrc = 96; src = w01; }
  else if (e < OW10)  { base = OW02;  kpad = 96;  Ksrc = 96;  Nsrc = 96; src = w02; }
  else if (e < OW11)  { base = OW10;  kpad = 192; Ksrc = 174; Nsrc = 96; src = w10; }
  else if (e < OW12)  { base = OW11;  kpad = 96;  Ksrc = 96;  Nsrc = 96; src = w11; }
  else if (e < OWPOST){ base = OW12;  kpad = 96;  Ksrc = 96;  Nsrc = 96; src = w12; }
  else                { base = OWPOST;kpad = 96;  Ksrc = 96;  Nsrc = 45; src = wpost; }
  int local = e - base;
  int n = local / kpad, k = local - n * kpad;
  float v = (k < Ksrc && n < Nsrc) ? src[k * Nsrc + n] : 0.f;
  unsigned short hi = f2bfu(v);
  ws[e]        = hi;
  ws[e + TOTW] = f2bfu(v - bfu2f(hi));
}

// ---- pre-kernel 2: ctxv [b][c][spat] -> ctxvt [b][spat][c] ----
__global__ __launch_bounds__(256) void transpose_ctxv(
    const float* __restrict__ src, float* __restrict__ dst)
{
  __shared__ float tile[96][65];
  const int blk = blockIdx.x;
  const int b = blk >> 9, s0 = (blk & 511) << 6;
  const int t = threadIdx.x;
  const int cq = t >> 6, sl = t & 63;
#pragma unroll
  for (int p = 0; p < 24; ++p) {
    int c = cq + p * 4;
    tile[c][sl] = src[(((size_t)(b * 96 + c)) << 15) + s0 + sl];
  }
  __syncthreads();
#pragma unroll
  for (int i = 0; i < 24; ++i) {
    int u = t + 256 * i;
    int s = u / 96, c = u - s * 96;
    dst[((size_t)(b << 15) + s0 + s) * 96 + c] = tile[c][s];
  }
}

// ---- layer GEMM: hi-only weights from global (L2-hot), double-buffered; acts bf16 LDS ----
// COORD layers: chunks 0..2 from pA; chunks 3..5 JIT-assembled per element from
// sTs (enc, bf16) / scw (cw,qw + zero slots) — all via one ds_read_u16 each.
template<int NM, int NC, bool COORD>
__device__ __forceinline__ void run_layer(
    const unsigned short* __restrict__ wmat, int kpad,
    const short* pA,
    const unsigned short* sTs, const unsigned short* scw,
    const float* __restrict__ bias, int biasN,
    float4v (&C)[NM][2], int lane, int rowb)
{
  const int ln15 = lane & 15, quad = lane >> 4;
#pragma unroll
  for (int mt = 0; mt < NM; ++mt) {
    int c0 = mt * 16 + quad * 4;
    float4v bv;
#pragma unroll
    for (int r = 0; r < 4; ++r) bv[r] = (c0 + r < biasN) ? bias[c0 + r] : 0.f;
    C[mt][0] = bv; C[mt][1] = bv;
  }
  short8 Wh[2][NM];
  auto loadW = [&](int cb, int buf) {
#pragma unroll
    for (int mt = 0; mt < NM; ++mt)
      Wh[buf][mt] = *(const short8*)(wmat + (mt * 16 + ln15) * kpad + cb * 32 + quad * 8);
  };
  loadW(0, 0);
#pragma unroll
  for (int cb = 0; cb < NC; ++cb) {
    const int cur = cb & 1;
    if (cb + 1 < NC) loadW(cb + 1, cur ^ 1);
    short8 Bh[2];
    if (COORD && cb >= 3) {
#pragma unroll
      for (int nt = 0; nt < 2; ++nt) {
        const int row = rowb + nt * 16 + ln15;
        const int q = row >> 3, cor = row & 7;
        short8 v8;
#pragma unroll
        for (int j = 0; j < 8; ++j) {
          int ch = (cb - 3) * 32 + quad * 8 + j;
          int i2 = ch - 6;
          int d  = (int)((unsigned)i2 / 24u);          // garbage if ch<6 (overridden)
          int rr = i2 - 24 * d;
          int sc = rr / 12, fj = rr - 12 * sc;
          int offd = (d == 0) ? ((cor >> 2) & 1) : (d == 1) ? ((cor >> 1) & 1) : (cor & 1);
          const unsigned short* p;
          if (ch < 6)        p = &scw[row * 8 + ch];       // cw/qw (centered)
          else if (ch >= 78) p = &scw[row * 8 + 6];        // zero slot
          else               p = &sTs[((q * 3 + d) * 2 + offd) * 24 + sc * 12 + fj];
          v8[j] = (short)*p;
        }
        Bh[nt] = v8;
      }
    } else {
      const int kofs = cb * 32;
#pragma unroll
      for (int nt = 0; nt < 2; ++nt)
        Bh[nt] = *(const short8*)&pA[(rowb + nt * 16 + ln15) * ASTR + kofs + quad * 8];
    }
#pragma unroll
    for (int mt = 0; mt < NM; ++mt)
#pragma unroll
      for (int nt = 0; nt < 2; ++nt)
        C[mt][nt] = __builtin_amdgcn_mfma_f32_16x16x32_bf16(Wh[cur][mt], Bh[nt], C[mt][nt], 0, 0, 0);
  }
}

template<bool TRANSPOSED>
__global__ __launch_bounds__(128, 3) void decoder_kernel(
    const float* __restrict__ ctxv,    // [2,96,32768]
    const float* __restrict__ ctxvt,   // [2,32768,96] (in ws) or alias
    const float* __restrict__ qwc,     // [2,32768,3]
    const float* __restrict__ aff,     // [2,4,4]
    const float* __restrict__ b01, const float* __restrict__ b02,
    const float* __restrict__ b11, const float* __restrict__ b12,
    const float* __restrict__ bpost,
    const unsigned short* __restrict__ ws,
    float* __restrict__ out)           // [2,45,32768]
{
  __shared__ __align__(16) short sY[64 * ASTR];       // skip accumulator (bf16), 64 rows
  __shared__ __align__(16) short sH[64 * ASTR];       // hidden (in-place) / pred f32
  __shared__ unsigned short sTs[1152];                // sincos table [8q][3d][2off][2sc][12fj]
  __shared__ unsigned short scw[64 * 8];              // per-row: cw0..2,qw0..2,0,0 (bf16)
  __shared__ float swtri[64];
  __shared__ int   sqbot[8][3];
  __shared__ float sqsub[8][3];
  __shared__ float sqw[8][3];
  // ~30.5 KB total -> 5 blocks/CU (10 waves) at <=4KB LDS granularity

  const int t = threadIdx.x;
  const int blk = blockIdx.x;
  const int b = blk >> 12;                  // 4096 blocks per batch
  const int qbase = (blk & 4095) * 8;
  const int lane = t & 63, wid = t >> 6;    // wid in {0,1}
  const int ln15 = lane & 15, quad = lane >> 4;
  const int rowb = wid * 32;
  const float* badj = (const float*)(ws + 2 * TOTW);

  // ---- per-query setup (8 threads, one query each) ----
  if (t < 8) {
    float m[4][8];
    for (int i = 0; i < 4; ++i)
      for (int j = 0; j < 4; ++j) {
        m[i][j] = aff[b * 16 + i * 4 + j];
        m[i][j + 4] = (i == j) ? 1.f : 0.f;
      }
    for (int col = 0; col < 4; ++col) {
      int piv = col; float best = fabsf(m[col][col]);
      for (int rr = col + 1; rr < 4; ++rr) {
        float v = fabsf(m[rr][col]);
        if (v > best) { best = v; piv = rr; }
      }
      if (piv != col)
        for (int j = 0; j < 8; ++j) { float tmp = m[col][j]; m[col][j] = m[piv][j]; m[piv][j] = tmp; }
      float d = 1.f / m[col][col];
      for (int j = 0; j < 8; ++j) m[col][j] *= d;
      for (int rr = 0; rr < 4; ++rr) if (rr != col) {
        float f = m[rr][col];
        for (int j = 0; j < 8; ++j) m[rr][j] -= f * m[col][j];
      }
    }
    int qi = qbase + t;
    float x = qwc[((size_t)b * NQv + qi) * 3 + 0];
    float y = qwc[((size_t)b * NQv + qi) * 3 + 1];
    float z = qwc[((size_t)b * NQv + qi) * 3 + 2];
    sqw[t][0] = x; sqw[t][1] = y; sqw[t][2] = z;
    float v0 = m[0][4] * x + m[0][5] * y + m[0][6] * z + m[0][7];
    float v1 = m[1][4] * x + m[1][5] * y + m[1][6] * z + m[1][7];
    float v2 = m[2][4] * x + m[2][5] * y + m[2][6] * z + m[2][7];
    int i0 = (int)floorf(v0), i1 = (int)floorf(v1), i2 = (int)floorf(v2);
    sqbot[t][0] = i0; sqbot[t][1] = i1; sqbot[t][2] = i2;
    sqsub[t][0] = v0 - (float)i0; sqsub[t][1] = v1 - (float)i1; sqsub[t][2] = v2 - (float)i2;
  }
  __syncthreads();

  // ---- block-wide sincos table build: 288 tasks = 8q x 3d x 12fj ----
#pragma unroll
  for (int i = 0; i < 3; ++i) {
    int u = t + 128 * i;
    if (u < 288) {
      int q = u / 36, rem = u - 36 * q, d = rem / 12, fj = rem - 12 * d;
      float sub = sqsub[q][d];
      float freq = exp2f((float)fj * 0.13208020839342968f);   // 3^(fj/12)
#pragma unroll
      for (int off = 0; off < 2; ++off) {
        float rel = (sub - (float)off + 1.f) * 0.5f;
        float ang = 6.283185307179586f * rel * freq;
        float sn, cs; __sincosf(ang, &sn, &cs);
        int base = ((q * 3 + d) * 2 + off) * 24 + fj;
        sTs[base]      = f2bfu(sn);   // sin block
        sTs[base + 12] = f2bfu(cs);   // cos block
      }
    }
  }
  __syncthreads();

  // ---- per-wave prologue: wtri + scw + Y (feats), rows rowb..rowb+31 ----
  if (lane < 32) {
    int row = rowb + lane;
    int q = row >> 3, cor = row & 7;
    int oi = (cor >> 2) & 1, oj = (cor >> 1) & 1, ok = cor & 1;
    float wx = oi ? sqsub[q][0] : 1.f - sqsub[q][0];
    float wy = oj ? sqsub[q][1] : 1.f - sqsub[q][1];
    float wz = ok ? sqsub[q][2] : 1.f - sqsub[q][2];
    swtri[row] = wx * wy * wz;
    scw[row * 8 + 0] = f2bfu((float)clamp31(sqbot[q][0] + oi) - 15.5f);
    scw[row * 8 + 1] = f2bfu((float)clamp31(sqbot[q][1] + oj) - 15.5f);
    scw[row * 8 + 2] = f2bfu((float)clamp31(sqbot[q][2] + ok) - 15.5f);
    scw[row * 8 + 3] = f2bfu(sqw[q][0] - 15.5f);
    scw[row * 8 + 4] = f2bfu(sqw[q][1] - 15.5f);
    scw[row * 8 + 5] = f2bfu(sqw[q][2] - 15.5f);
    scw[row * 8 + 6] = 0;
    scw[row * 8 + 7] = 0;
  }
  {
    const int row = rowb + (lane >> 1);
    const int q = row >> 3, cor = row & 7;
    const int oi = (cor >> 2) & 1, oj = (cor >> 1) & 1, ok = cor & 1;
    const int jb = (lane & 1) * 48;
    const int ix = clamp31(sqbot[q][0] + oi);
    const int iy = clamp31(sqbot[q][1] + oj);
    const int iz = clamp31(sqbot[q][2] + ok);
    const int spat = (ix << 10) | (iy << 5) | iz;
    if (TRANSPOSED) {
      const float* src = ctxvt + ((size_t)(b << 15) + spat) * 96 + jb;
#pragma unroll
      for (int g = 0; g < 12; ++g) {
        float4v v = *(const float4v*)(src + 4 * g);
        *(uint2*)&sY[row * ASTR + jb + 4 * g] = make_uint2(pkp(v[0], v[1]), pkp(v[2], v[3]));
      }
    } else {
#pragma unroll 4
      for (int g = 0; g < 12; ++g) {
        float vv[4];
#pragma unroll
        for (int r = 0; r < 4; ++r)
          vv[r] = ctxv[(((size_t)(b * 96 + jb + 4 * g + r)) << 15) + spat];
        *(uint2*)&sY[row * ASTR + jb + 4 * g] = make_uint2(pkp(vv[0], vv[1]), pkp(vv[2], vv[3]));
      }
    }
  }
  // no barrier: sY/sH/scw rows are wave-local; sTs guarded by the barrier above

  auto epiH = [&](float4v (&C)[6][2]) {
#pragma unroll
    for (int mt = 0; mt < 6; ++mt)
#pragma unroll
      for (int nt = 0; nt < 2; ++nt) {
        int idx = (rowb + nt * 16 + ln15) * ASTR + mt * 16 + quad * 4;
        *(uint2*)&sH[idx] = make_uint2(pkp(silu_f(C[mt][nt][0]), silu_f(C[mt][nt][1])),
                                       pkp(silu_f(C[mt][nt][2]), silu_f(C[mt][nt][3])));
      }
  };
  auto epiSkip = [&](float4v (&C)[6][2]) {
#pragma unroll
    for (int mt = 0; mt < 6; ++mt)
#pragma unroll
      for (int nt = 0; nt < 2; ++nt) {
        int idx = (rowb + nt * 16 + ln15) * ASTR + mt * 16 + quad * 4;
        uint2 oh = *(uint2*)&sY[idx];
        float y0 = __uint_as_float(oh.x << 16)          + silu_f(C[mt][nt][0]);
        float y1 = __uint_as_float(oh.x & 0xffff0000u)  + silu_f(C[mt][nt][1]);
        float y2 = __uint_as_float(oh.y << 16)          + silu_f(C[mt][nt][2]);
        float y3 = __uint_as_float(oh.y & 0xffff0000u)  + silu_f(C[mt][nt][3]);
        *(uint2*)&sY[idx] = make_uint2(pkp(y0, y1), pkp(y2, y3));
      }
  };

  {
    float4v C[6][2];
    run_layer<6, 6, true >(ws + OW00, 192, sY, sTs, scw, badj,      96, C, lane, rowb);
    epiH(C);
    run_layer<6, 3, false>(ws + OW01, 96,  sH, sTs, scw, b01,       96, C, lane, rowb);
    epiH(C);
    run_layer<6, 3, false>(ws + OW02, 96,  sH, sTs, scw, b02,       96, C, lane, rowb);
    epiSkip(C);
    run_layer<6, 6, true >(ws + OW10, 192, sY, sTs, scw, badj + 96, 96, C, lane, rowb);
    epiH(C);
    run_layer<6, 3, false>(ws + OW11, 96,  sH, sTs, scw, b11,       96, C, lane, rowb);
    epiH(C);
    run_layer<6, 3, false>(ws + OW12, 96,  sH, sTs, scw, b12,       96, C, lane, rowb);
    epiSkip(C);
  }
  float* pred = (float*)sH;                 // [64][52] f32 view of sH rows
  {
    float4v Cp[3][2];
    run_layer<3, 3, false>(ws + OWPOST, 96, sY, sTs, scw, bpost, 45, Cp, lane, rowb);
#pragma unroll
    for (int mt = 0; mt < 3; ++mt)
#pragma unroll
      for (int nt = 0; nt < 2; ++nt) {
        int row = rowb + nt * 16 + ln15, c0 = mt * 16 + quad * 4;
        float w = swtri[row];
        float4v v = Cp[mt][nt];
        v[0] *= w; v[1] *= w; v[2] *= w; v[3] *= w;
        *(float4v*)&pred[row * 52 + c0] = v;
      }
  }
  // ---- per-wave trilinear combine (queries wid*4..wid*4+3) + store ----
#pragma unroll
  for (int i = 0; i < 3; ++i) {
    int u = lane + 64 * i;
    if (u < 180) {
      int ql = u / 45, ch = u - ql * 45;
      float s = 0.f;
#pragma unroll
      for (int cor = 0; cor < 8; ++cor) s += pred[(rowb + ql * 8 + cor) * 52 + ch];
      out[(((size_t)(b * 45 + ch)) << 15) + qbase + wid * 4 + ql] = s;
    }
  }
}

extern "C" void kernel_launch(void* const* d_in, const int* in_sizes, int n_in,
                              void* d_out, int out_size, void* d_ws, size_t ws_size,
                              hipStream_t stream) {
  (void)in_sizes; (void)n_in; (void)out_size;
  const float* ctxv  = (const float*)d_in[0];
  const float* qwc   = (const float*)d_in[2];
  const float* aff   = (const float*)d_in[4];
  const float* w00   = (const float*)d_in[8];
  const float* b00   = (const float*)d_in[9];
  const float* w01   = (const float*)d_in[10];
  const float* b01   = (const float*)d_in[11];
  const float* w02   = (const float*)d_in[12];
  const float* b02   = (const float*)d_in[13];
  const float* w10   = (const float*)d_in[14];
  const float* b10   = (const float*)d_in[15];
  const float* w11   = (const float*)d_in[16];
  const float* b11   = (const float*)d_in[17];
  const float* w12   = (const float*)d_in[18];
  const float* b12   = (const float*)d_in[19];
  const float* wpost = (const float*)d_in[20];
  const float* bpost = (const float*)d_in[21];
  unsigned short* ws = (unsigned short*)d_ws;
  float* out = (float*)d_out;

  const size_t wbytes = (size_t)TOTW * 2 * sizeof(unsigned short) + 768;
  const size_t tbytes = (size_t)2 * 32768 * 96 * sizeof(float);
  float* ctxvt = (float*)((char*)d_ws + wbytes);
  const bool useT = ws_size >= wbytes + tbytes;

  convert_weights<<<dim3((TOTW + 192 + 255) / 256), dim3(256), 0, stream>>>(
      w00, w01, w02, w10, w11, w12, wpost, b00, b10, ws);
  if (useT) {
    transpose_ctxv<<<dim3(1024), dim3(256), 0, stream>>>(ctxv, ctxvt);
    decoder_kernel<true><<<dim3(8192), dim3(128), 0, stream>>>(
        ctxv, ctxvt, qwc, aff, b01, b02, b11, b12, bpost, ws, out);
  } else {
    decoder_kernel<false><<<dim3(8192), dim3(128), 0, stream>>>(
        ctxv, ctxv, qwc, aff, b01, b02, b11, b12, bpost, ws, out);
  }
}

// Round 15
// 433.262 us; speedup vs baseline: 1.3446x; 1.3446x over previous
//
#include <hip/hip_runtime.h>

#define NQv   32768
#define TOTW  78336
#define OW00  0
#define OW01  18432
#define OW02  27648
#define OW10  36864
#define OW11  55296
#define OW12  64512
#define OWPOST 73728
#define ASTR  104     // feats/hidden plane stride in shorts (208B = 13*16B)
#define CSTR  80      // coord plane stride in shorts (160B, 16B-aligned)

typedef __attribute__((ext_vector_type(8))) short  short8;
typedef __attribute__((ext_vector_type(4))) float  float4v;

__device__ __forceinline__ float bfu2f(unsigned short u) {
  return __uint_as_float(((unsigned int)u) << 16);
}
__device__ __forceinline__ unsigned short f2bfu(float f) {
  unsigned int x = __float_as_uint(f);
  x += 0x7fffu + ((x >> 16) & 1u);   // RNE
  return (unsigned short)(x >> 16);
}
// ties-away bf16 round, result in bits [31:16]
__device__ __forceinline__ unsigned int rnd16(float f) {
  return __float_as_uint(f) + 0x8000u;
}
// pack two floats -> (bf16(hi)<<16)|bf16(lo) in 3 VALU
__device__ __forceinline__ unsigned int pkp(float lo, float hi) {
  return __builtin_amdgcn_perm(rnd16(hi), rnd16(lo), 0x07060302u);
}
__device__ __forceinline__ float silu_f(float x) { return x / (1.f + __expf(-x)); }
__device__ __forceinline__ int clamp31(int v) { return min(max(v, 0), 31); }

// ---- pre-kernel 1: weights -> bf16 hi/lo [n][kpad] + centered-coord bias adjust ----
__global__ __launch_bounds__(256) void convert_weights(
    const float* __restrict__ w00, const float* __restrict__ w01,
    const float* __restrict__ w02, const float* __restrict__ w10,
    const float* __restrict__ w11, const float* __restrict__ w12,
    const float* __restrict__ wpost,
    const float* __restrict__ b00, const float* __restrict__ b10,
    unsigned short* __restrict__ ws)
{
  int e = blockIdx.x * 256 + threadIdx.x;
  if (e >= TOTW + 192) return;
  if (e >= TOTW) {
    int e2 = e - TOTW, mat = e2 / 96, ch = e2 - mat * 96;
    const float* w = mat ? w10 : w00;
    const float* bb = mat ? b10 : b00;
    float s = bb[ch];
#pragma unroll
    for (int k = 0; k < 6; ++k) s += 15.5f * w[(96 + k) * 96 + ch];
    ((float*)(ws + 2 * TOTW))[e2] = s;
    return;
  }
  int base, kpad, Ksrc, Nsrc; const float* src;
  if      (e < OW01)  { base = OW00;  kpad = 192; Ksrc = 174; Nsrc = 96; src = w00; }
  else if (e < OW02)  { base = OW01;  kpad = 96;  Ksrc = 96;  Nsrc = 96; src = w01; }
  else if (e < OW10)  { base = OW02;  kpad = 96;  Ksrc = 96;  Nsrc = 96; src = w02; }
  else if (e < OW11)  { base = OW10;  kpad = 192; Ksrc = 174; Nsrc = 96; src = w10; }
  else if (e < OW12)  { base = OW11;  kpad = 96;  Ksrc = 96;  Nsrc = 96; src = w11; }
  else if (e < OWPOST){ base = OW12;  kpad = 96;  Ksrc = 96;  Nsrc = 96; src = w12; }
  else                { base = OWPOST;kpad = 96;  Ksrc = 96;  Nsrc = 45; src = wpost; }
  int local = e - base;
  int n = local / kpad, k = local - n * kpad;
  float v = (k < Ksrc && n < Nsrc) ? src[k * Nsrc + n] : 0.f;
  unsigned short hi = f2bfu(v);
  ws[e]        = hi;
  ws[e + TOTW] = f2bfu(v - bfu2f(hi));
}

// ---- pre-kernel 2: ctxv [b][c][spat] -> ctxvt [b][spat][c] ----
__global__ __launch_bounds__(256) void transpose_ctxv(
    const float* __restrict__ src, float* __restrict__ dst)
{
  __shared__ float tile[96][65];
  const int blk = blockIdx.x;
  const int b = blk >> 9, s0 = (blk & 511) << 6;
  const int t = threadIdx.x;
  const int cq = t >> 6, sl = t & 63;
#pragma unroll
  for (int p = 0; p < 24; ++p) {
    int c = cq + p * 4;
    tile[c][sl] = src[(((size_t)(b * 96 + c)) << 15) + s0 + sl];
  }
  __syncthreads();
#pragma unroll
  for (int i = 0; i < 24; ++i) {
    int u = t + 256 * i;
    int s = u / 96, c = u - s * 96;
    dst[((size_t)(b << 15) + s0 + s) * 96 + c] = tile[c][s];
  }
}

// ---- layer GEMM: hi-only weights from global (L2-hot), DEPTH-3 prefetch; acts bf16 LDS ----
// COORD layers: chunks 0..2 from pA (stride ASTR), chunks 3..5 from pC (stride CSTR);
// chunk 5 quads 2..3 are structurally zero channels -> zero B-fragment.
template<int NM, int NC, bool COORD>
__device__ __forceinline__ void run_layer(
    const unsigned short* __restrict__ wmat, int kpad,
    const short* pA, const short* pC,
    const float* __restrict__ bias, int biasN,
    float4v (&C)[NM][2], int lane, int rowb)
{
  const int ln15 = lane & 15, quad = lane >> 4;
#pragma unroll
  for (int mt = 0; mt < NM; ++mt) {
    int c0 = mt * 16 + quad * 4;
    float4v bv;
#pragma unroll
    for (int r = 0; r < 4; ++r) bv[r] = (c0 + r < biasN) ? bias[c0 + r] : 0.f;
    C[mt][0] = bv; C[mt][1] = bv;
  }
  short8 Wh[3][NM];                       // depth-3 rotating weight buffer
  auto loadW = [&](int cb, int buf) {
#pragma unroll
    for (int mt = 0; mt < NM; ++mt)
      Wh[buf][mt] = *(const short8*)(wmat + (mt * 16 + ln15) * kpad + cb * 32 + quad * 8);
  };
  loadW(0, 0);
  if (NC > 1) loadW(1, 1);
  if (NC > 2) loadW(2, 2);
#pragma unroll
  for (int cb = 0; cb < NC; ++cb) {
    const int cur = cb % 3;
    short8 Bh[2];
    if (COORD && cb >= 3) {
      const int kofs = (cb - 3) * 32;
#pragma unroll
      for (int nt = 0; nt < 2; ++nt) {
        if (cb == 5 && quad >= 2) {
          Bh[nt] = (short8)0;             // channels 80..95 are zero
        } else {
          Bh[nt] = *(const short8*)&pC[(rowb + nt * 16 + ln15) * CSTR + kofs + quad * 8];
        }
      }
    } else {
      const int kofs = cb * 32;
#pragma unroll
      for (int nt = 0; nt < 2; ++nt)
        Bh[nt] = *(const short8*)&pA[(rowb + nt * 16 + ln15) * ASTR + kofs + quad * 8];
    }
#pragma unroll
    for (int mt = 0; mt < NM; ++mt)
#pragma unroll
      for (int nt = 0; nt < 2; ++nt)
        C[mt][nt] = __builtin_amdgcn_mfma_f32_16x16x32_bf16(Wh[cur][mt], Bh[nt], C[mt][nt], 0, 0, 0);
    if (cb + 3 < NC) loadW(cb + 3, cur);  // refill the buffer just consumed
  }
}

template<bool TRANSPOSED>
__global__ __launch_bounds__(256, 2) void decoder_kernel(
    const float* __restrict__ ctxv,    // [2,96,32768]
    const float* __restrict__ ctxvt,   // [2,32768,96] (in ws) or alias
    const float* __restrict__ qwc,     // [2,32768,3]
    const float* __restrict__ aff,     // [2,4,4]
    const float* __restrict__ b01, const float* __restrict__ b02,
    const float* __restrict__ b11, const float* __restrict__ b12,
    const float* __restrict__ bpost,
    const unsigned short* __restrict__ ws,
    float* __restrict__ out)           // [2,45,32768]
{
  __shared__ __align__(16) short sY[128 * ASTR];      // skip accumulator (bf16)
  __shared__ __align__(16) short sC[128 * CSTR];      // coord plane (bf16, 80 ch)
  __shared__ __align__(16) short sH[128 * ASTR];      // hidden (in-place) / pred f32
  __shared__ unsigned short sTs[2304];                // sincos table [16q][3d][2off][2sc][12fj]
  __shared__ float swtri[128];
  __shared__ int   sqbot[16][3];
  __shared__ float sqsub[16][3];
  // total ~79.2 KB -> 2 blocks/CU

  const int t = threadIdx.x;
  const int blk = blockIdx.x;
  const int b = blk >> 11;
  const int qbase = (blk & 2047) * 16;
  const int lane = t & 63, wid = t >> 6;
  const int ln15 = lane & 15, quad = lane >> 4;
  const int rowb = wid * 32;
  const float* badj = (const float*)(ws + 2 * TOTW);

  // ---- per-query setup (wave 0, 16 threads) ----
  if (t < 16) {
    float m[4][8];
    for (int i = 0; i < 4; ++i)
      for (int j = 0; j < 4; ++j) {
        m[i][j] = aff[b * 16 + i * 4 + j];
        m[i][j + 4] = (i == j) ? 1.f : 0.f;
      }
    for (int col = 0; col < 4; ++col) {
      int piv = col; float best = fabsf(m[col][col]);
      for (int rr = col + 1; rr < 4; ++rr) {
        float v = fabsf(m[rr][col]);
        if (v > best) { best = v; piv = rr; }
      }
      if (piv != col)
        for (int j = 0; j < 8; ++j) { float tmp = m[col][j]; m[col][j] = m[piv][j]; m[piv][j] = tmp; }
      float d = 1.f / m[col][col];
      for (int j = 0; j < 8; ++j) m[col][j] *= d;
      for (int rr = 0; rr < 4; ++rr) if (rr != col) {
        float f = m[rr][col];
        for (int j = 0; j < 8; ++j) m[rr][j] -= f * m[col][j];
      }
    }
    int qi = qbase + t;
    float x = qwc[((size_t)b * NQv + qi) * 3 + 0];
    float y = qwc[((size_t)b * NQv + qi) * 3 + 1];
    float z = qwc[((size_t)b * NQv + qi) * 3 + 2];
    float v0 = m[0][4] * x + m[0][5] * y + m[0][6] * z + m[0][7];
    float v1 = m[1][4] * x + m[1][5] * y + m[1][6] * z + m[1][7];
    float v2 = m[2][4] * x + m[2][5] * y + m[2][6] * z + m[2][7];
    int i0 = (int)floorf(v0), i1 = (int)floorf(v1), i2 = (int)floorf(v2);
    sqbot[t][0] = i0; sqbot[t][1] = i1; sqbot[t][2] = i2;
    sqsub[t][0] = v0 - (float)i0; sqsub[t][1] = v1 - (float)i1; sqsub[t][2] = v2 - (float)i2;
  }
  __syncthreads();

  // ---- block-wide sincos table build: 576 tasks = 16q x 3d x 12fj ----
#pragma unroll
  for (int i = 0; i < 3; ++i) {
    int u = t + 256 * i;
    if (u < 576) {
      int q = u / 36, rem = u - 36 * q, d = rem / 12, fj = rem - 12 * d;
      float sub = sqsub[q][d];
      float freq = exp2f((float)fj * 0.13208020839342968f);   // 3^(fj/12)
#pragma unroll
      for (int off = 0; off < 2; ++off) {
        float rel = (sub - (float)off + 1.f) * 0.5f;
        float ang = 6.283185307179586f * rel * freq;
        float sn, cs; __sincosf(ang, &sn, &cs);
        int base = ((q * 3 + d) * 2 + off) * 24 + fj;
        sTs[base]      = f2bfu(sn);   // sc=0 (sin)
        sTs[base + 12] = f2bfu(cs);   // sc=1 (cos)
      }
    }
  }
  __syncthreads();

  // ---- per-wave prologue: wtri + Y (feats) + COORD planes (rows rowb..rowb+31) ----
  if (lane < 32) {
    int row = rowb + lane;
    int q = row >> 3, cor = row & 7;
    int oi = (cor >> 2) & 1, oj = (cor >> 1) & 1, ok = cor & 1;
    float wx = oi ? sqsub[q][0] : 1.f - sqsub[q][0];
    float wy = oj ? sqsub[q][1] : 1.f - sqsub[q][1];
    float wz = ok ? sqsub[q][2] : 1.f - sqsub[q][2];
    swtri[row] = wx * wy * wz;
  }
  {
    const int row = rowb + (lane >> 1);
    const int q = row >> 3, cor = row & 7;
    const int oi = (cor >> 2) & 1, oj = (cor >> 1) & 1, ok = cor & 1;
    const int jb = (lane & 1) * 48;
    const int ix = clamp31(sqbot[q][0] + oi);
    const int iy = clamp31(sqbot[q][1] + oj);
    const int iz = clamp31(sqbot[q][2] + ok);
    const int spat = (ix << 10) | (iy << 5) | iz;
    // Y = feats
    if (TRANSPOSED) {
      const float* src = ctxvt + ((size_t)(b << 15) + spat) * 96 + jb;
#pragma unroll
      for (int g = 0; g < 12; ++g) {
        float4v v = *(const float4v*)(src + 4 * g);
        *(uint2*)&sY[row * ASTR + jb + 4 * g] = make_uint2(pkp(v[0], v[1]), pkp(v[2], v[3]));
      }
    } else {
#pragma unroll 4
      for (int g = 0; g < 12; ++g) {
        float vv[4];
#pragma unroll
        for (int r = 0; r < 4; ++r)
          vv[r] = ctxv[(((size_t)(b * 96 + jb + 4 * g + r)) << 15) + spat];
        *(uint2*)&sY[row * ASTR + jb + 4 * g] = make_uint2(pkp(vv[0], vv[1]), pkp(vv[2], vv[3]));
      }
    }
    // COORD plane (80 ch): [cw-15.5(3) qw-15.5(3) enc(72) pad(2)] from table
    int offv[3]; offv[0] = oi; offv[1] = oj; offv[2] = ok;
    const int cbase = (lane & 1) * 40;
    float qw3[3];
#pragma unroll
    for (int k = 0; k < 3; ++k) qw3[k] = qwc[((size_t)b * NQv + qbase + q) * 3 + k];
#pragma unroll
    for (int g = 0; g < 10; ++g) {
      unsigned short hv[4];
#pragma unroll
      for (int r = 0; r < 4; ++r) {
        int ch = cbase + 4 * g + r;
        if (ch < 3) {
          float v = (float)clamp31(sqbot[q][ch] + offv[ch]) - 15.5f;
          hv[r] = (unsigned short)(rnd16(v) >> 16);
        } else if (ch < 6) {
          float v = qw3[ch - 3] - 15.5f;
          hv[r] = (unsigned short)(rnd16(v) >> 16);
        } else if (ch < 78) {
          int i2 = ch - 6, d = i2 / 24, rr = i2 - 24 * d, sc = rr / 12, fj = rr - 12 * sc;
          hv[r] = sTs[(((q * 3 + d) * 2 + offv[d]) * 2 + sc) * 12 + fj];
        } else hv[r] = 0;
      }
      *(uint2*)&sC[row * CSTR + cbase + 4 * g] =
          make_uint2((unsigned int)hv[0] | ((unsigned int)hv[1] << 16),
                     (unsigned int)hv[2] | ((unsigned int)hv[3] << 16));
    }
  }
  // no barrier: planes are wave-local from here on

  auto epiH = [&](float4v (&C)[6][2]) {
#pragma unroll
    for (int mt = 0; mt < 6; ++mt)
#pragma unroll
      for (int nt = 0; nt < 2; ++nt) {
        int idx = (rowb + nt * 16 + ln15) * ASTR + mt * 16 + quad * 4;
        *(uint2*)&sH[idx] = make_uint2(pkp(silu_f(C[mt][nt][0]), silu_f(C[mt][nt][1])),
                                       pkp(silu_f(C[mt][nt][2]), silu_f(C[mt][nt][3])));
      }
  };
  auto epiSkip = [&](float4v (&C)[6][2]) {
#pragma unroll
    for (int mt = 0; mt < 6; ++mt)
#pragma unroll
      for (int nt = 0; nt < 2; ++nt) {
        int idx = (rowb + nt * 16 + ln15) * ASTR + mt * 16 + quad * 4;
        uint2 oh = *(uint2*)&sY[idx];
        float y0 = __uint_as_float(oh.x << 16)          + silu_f(C[mt][nt][0]);
        float y1 = __uint_as_float(oh.x & 0xffff0000u)  + silu_f(C[mt][nt][1]);
        float y2 = __uint_as_float(oh.y << 16)          + silu_f(C[mt][nt][2]);
        float y3 = __uint_as_float(oh.y & 0xffff0000u)  + silu_f(C[mt][nt][3]);
        *(uint2*)&sY[idx] = make_uint2(pkp(y0, y1), pkp(y2, y3));
      }
  };

  {
    float4v C[6][2];
    run_layer<6, 6, true >(ws + OW00, 192, sY, sC, badj,      96, C, lane, rowb);
    epiH(C);
    run_layer<6, 3, false>(ws + OW01, 96,  sH, sC, b01,       96, C, lane, rowb);
    epiH(C);
    run_layer<6, 3, false>(ws + OW02, 96,  sH, sC, b02,       96, C, lane, rowb);
    epiSkip(C);
    run_layer<6, 6, true >(ws + OW10, 192, sY, sC, badj + 96, 96, C, lane, rowb);
    epiH(C);
    run_layer<6, 3, false>(ws + OW11, 96,  sH, sC, b11,       96, C, lane, rowb);
    epiH(C);
    run_layer<6, 3, false>(ws + OW12, 96,  sH, sC, b12,       96, C, lane, rowb);
    epiSkip(C);
  }
  float* pred = (float*)sH;                 // [row][52] f32 view of sH rows
  {
    float4v Cp[3][2];
    run_layer<3, 3, false>(ws + OWPOST, 96, sY, sC, bpost, 45, Cp, lane, rowb);
#pragma unroll
    for (int mt = 0; mt < 3; ++mt)
#pragma unroll
      for (int nt = 0; nt < 2; ++nt) {
        int row = rowb + nt * 16 + ln15, c0 = mt * 16 + quad * 4;
        float w = swtri[row];
        float4v v = Cp[mt][nt];
        v[0] *= w; v[1] *= w; v[2] *= w; v[3] *= w;
        *(float4v*)&pred[row * 52 + c0] = v;
      }
  }
  // ---- per-wave trilinear combine (queries wid*4..wid*4+3) + store ----
#pragma unroll
  for (int i = 0; i < 3; ++i) {
    int u = lane + 64 * i;
    if (u < 180) {
      int ql = u / 45, ch = u - ql * 45;
      float s = 0.f;
#pragma unroll
      for (int cor = 0; cor < 8; ++cor) s += pred[(rowb + ql * 8 + cor) * 52 + ch];
      out[(((size_t)(b * 45 + ch)) << 15) + qbase + wid * 4 + ql] = s;
    }
  }
}

extern "C" void kernel_launch(void* const* d_in, const int* in_sizes, int n_in,
                              void* d_out, int out_size, void* d_ws, size_t ws_size,
                              hipStream_t stream) {
  (void)in_sizes; (void)n_in; (void)out_size;
  const float* ctxv  = (const float*)d_in[0];
  const float* qwc   = (const float*)d_in[2];
  const float* aff   = (const float*)d_in[4];
  const float* w00   = (const float*)d_in[8];
  const float* b00   = (const float*)d_in[9];
  const float* w01   = (const float*)d_in[10];
  const float* b01   = (const float*)d_in[11];
  const float* w02   = (const float*)d_in[12];
  const float* b02   = (const float*)d_in[13];
  const float* w10   = (const float*)d_in[14];
  const float* b10   = (const float*)d_in[15];
  const float* w11   = (const float*)d_in[16];
  const float* b11   = (const float*)d_in[17];
  const float* w12   = (const float*)d_in[18];
  const float* b12   = (const float*)d_in[19];
  const float* wpost = (const float*)d_in[20];
  const float* bpost = (const float*)d_in[21];
  unsigned short* ws = (unsigned short*)d_ws;
  float* out = (float*)d_out;

  const size_t wbytes = (size_t)TOTW * 2 * sizeof(unsigned short) + 768;
  const size_t tbytes = (size_t)2 * 32768 * 96 * sizeof(float);
  float* ctxvt = (float*)((char*)d_ws + wbytes);
  const bool useT = ws_size >= wbytes + tbytes;

  convert_weights<<<dim3((TOTW + 192 + 255) / 256), dim3(256), 0, stream>>>(
      w00, w01, w02, w10, w11, w12, wpost, b00, b10, ws);
  if (useT) {
    transpose_ctxv<<<dim3(1024), dim3(256), 0, stream>>>(ctxv, ctxvt);
    decoder_kernel<true><<<dim3(4096), dim3(256), 0, stream>>>(
        ctxv, ctxvt, qwc, aff, b01, b02, b11, b12, bpost, ws, out);
  } else {
    decoder_kernel<false><<<dim3(4096), dim3(256), 0, stream>>>(
        ctxv, ctxv, qwc, aff, b01, b02, b11, b12, bpost, ws, out);
  }
}

// Round 16
// 384.991 us; speedup vs baseline: 1.5132x; 1.1254x over previous
//
#include <hip/hip_runtime.h>

#define NQv   32768
#define TOTW  78336
#define OW00  0
#define OW01  18432
#define OW02  27648
#define OW10  36864
#define OW11  55296
#define OW12  64512
#define OWPOST 73728
#define ASTR  104     // feats/hidden plane stride in shorts (208B = 13*16B)
#define CSTR  80      // coord plane stride in shorts (160B, 16B-aligned)

typedef __attribute__((ext_vector_type(8))) short  short8;
typedef __attribute__((ext_vector_type(4))) float  float4v;

__device__ __forceinline__ float bfu2f(unsigned short u) {
  return __uint_as_float(((unsigned int)u) << 16);
}
__device__ __forceinline__ unsigned short f2bfu(float f) {
  unsigned int x = __float_as_uint(f);
  x += 0x7fffu + ((x >> 16) & 1u);   // RNE
  return (unsigned short)(x >> 16);
}
// ties-away bf16 round, result in bits [31:16]
__device__ __forceinline__ unsigned int rnd16(float f) {
  return __float_as_uint(f) + 0x8000u;
}
// pack two floats -> (bf16(hi)<<16)|bf16(lo) in 3 VALU
__device__ __forceinline__ unsigned int pkp(float lo, float hi) {
  return __builtin_amdgcn_perm(rnd16(hi), rnd16(lo), 0x07060302u);
}
// silu via HW reciprocal (v_rcp_f32, ~1 ulp) instead of the ~10-instr f32 divide
__device__ __forceinline__ float silu_f(float x) {
  float e = __expf(-x);
  return x * __builtin_amdgcn_rcpf(1.f + e);
}
__device__ __forceinline__ int clamp31(int v) { return min(max(v, 0), 31); }

// ---- pre-kernel 1: weights -> bf16 hi/lo [n][kpad] + centered-coord bias adjust ----
__global__ __launch_bounds__(256) void convert_weights(
    const float* __restrict__ w00, const float* __restrict__ w01,
    const float* __restrict__ w02, const float* __restrict__ w10,
    const float* __restrict__ w11, const float* __restrict__ w12,
    const float* __restrict__ wpost,
    const float* __restrict__ b00, const float* __restrict__ b10,
    unsigned short* __restrict__ ws)
{
  int e = blockIdx.x * 256 + threadIdx.x;
  if (e >= TOTW + 192) return;
  if (e >= TOTW) {
    int e2 = e - TOTW, mat = e2 / 96, ch = e2 - mat * 96;
    const float* w = mat ? w10 : w00;
    const float* bb = mat ? b10 : b00;
    float s = bb[ch];
#pragma unroll
    for (int k = 0; k < 6; ++k) s += 15.5f * w[(96 + k) * 96 + ch];
    ((float*)(ws + 2 * TOTW))[e2] = s;
    return;
  }
  int base, kpad, Ksrc, Nsrc; const float* src;
  if      (e < OW01)  { base = OW00;  kpad = 192; Ksrc = 174; Nsrc = 96; src = w00; }
  else if (e < OW02)  { base = OW01;  kpad = 96;  Ksrc = 96;  Nsrc = 96; src = w01; }
  else if (e < OW10)  { base = OW02;  kpad = 96;  Ksrc = 96;  Nsrc = 96; src = w02; }
  else if (e < OW11)  { base = OW10;  kpad = 192; Ksrc = 174; Nsrc = 96; src = w10; }
  else if (e < OW12)  { base = OW11;  kpad = 96;  Ksrc = 96;  Nsrc = 96; src = w11; }
  else if (e < OWPOST){ base = OW12;  kpad = 96;  Ksrc = 96;  Nsrc = 96; src = w12; }
  else                { base = OWPOST;kpad = 96;  Ksrc = 96;  Nsrc = 45; src = wpost; }
  int local = e - base;
  int n = local / kpad, k = local - n * kpad;
  float v = (k < Ksrc && n < Nsrc) ? src[k * Nsrc + n] : 0.f;
  unsigned short hi = f2bfu(v);
  ws[e]        = hi;
  ws[e + TOTW] = f2bfu(v - bfu2f(hi));
}

// ---- pre-kernel 2: ctxv [b][c][spat] -> ctxvt [b][spat][c] ----
__global__ __launch_bounds__(256) void transpose_ctxv(
    const float* __restrict__ src, float* __restrict__ dst)
{
  __shared__ float tile[96][65];
  const int blk = blockIdx.x;
  const int b = blk >> 9, s0 = (blk & 511) << 6;
  const int t = threadIdx.x;
  const int cq = t >> 6, sl = t & 63;
#pragma unroll
  for (int p = 0; p < 24; ++p) {
    int c = cq + p * 4;
    tile[c][sl] = src[(((size_t)(b * 96 + c)) << 15) + s0 + sl];
  }
  __syncthreads();
#pragma unroll
  for (int i = 0; i < 24; ++i) {
    int u = t + 256 * i;
    int s = u / 96, c = u - s * 96;
    dst[((size_t)(b << 15) + s0 + s) * 96 + c] = tile[c][s];
  }
}

// ---- layer GEMM: hi-only weights from global (L2-hot), depth-3 prefetch; acts bf16 LDS ----
// COORD layers: chunks 0..2 from pA (stride ASTR), chunks 3..5 from pC (stride CSTR);
// chunk 5 quads 2..3 are structurally zero channels -> zero B-fragment.
template<int NM, int NC, bool COORD>
__device__ __forceinline__ void run_layer(
    const unsigned short* __restrict__ wmat, int kpad,
    const short* pA, const short* pC,
    const float* __restrict__ bias, int biasN,
    float4v (&C)[NM][2], int lane, int rowb)
{
  const int ln15 = lane & 15, quad = lane >> 4;
  if (biasN >= NM * 16) {
#pragma unroll
    for (int mt = 0; mt < NM; ++mt) {
      float4v bv = *(const float4v*)(bias + mt * 16 + quad * 4);
      C[mt][0] = bv; C[mt][1] = bv;
    }
  } else {
#pragma unroll
    for (int mt = 0; mt < NM; ++mt) {
      int c0 = mt * 16 + quad * 4;
      float4v bv;
#pragma unroll
      for (int r = 0; r < 4; ++r) bv[r] = (c0 + r < biasN) ? bias[c0 + r] : 0.f;
      C[mt][0] = bv; C[mt][1] = bv;
    }
  }
  short8 Wh[3][NM];                       // depth-3 rotating weight buffer
  auto loadW = [&](int cb, int buf) {
#pragma unroll
    for (int mt = 0; mt < NM; ++mt)
      Wh[buf][mt] = *(const short8*)(wmat + (mt * 16 + ln15) * kpad + cb * 32 + quad * 8);
  };
  loadW(0, 0);
  if (NC > 1) loadW(1, 1);
  if (NC > 2) loadW(2, 2);
#pragma unroll
  for (int cb = 0; cb < NC; ++cb) {
    const int cur = cb % 3;
    short8 Bh[2];
    if (COORD && cb >= 3) {
      const int kofs = (cb - 3) * 32;
#pragma unroll
      for (int nt = 0; nt < 2; ++nt) {
        if (cb == 5 && quad >= 2) {
          Bh[nt] = (short8)0;             // channels 80..95 are zero
        } else {
          Bh[nt] = *(const short8*)&pC[(rowb + nt * 16 + ln15) * CSTR + kofs + quad * 8];
        }
      }
    } else {
      const int kofs = cb * 32;
#pragma unroll
      for (int nt = 0; nt < 2; ++nt)
        Bh[nt] = *(const short8*)&pA[(rowb + nt * 16 + ln15) * ASTR + kofs + quad * 8];
    }
#pragma unroll
    for (int mt = 0; mt < NM; ++mt)
#pragma unroll
      for (int nt = 0; nt < 2; ++nt)
        C[mt][nt] = __builtin_amdgcn_mfma_f32_16x16x32_bf16(Wh[cur][mt], Bh[nt], C[mt][nt], 0, 0, 0);
    if (cb + 3 < NC) loadW(cb + 3, cur);  // refill the buffer just consumed
  }
}

template<bool TRANSPOSED>
__global__ __launch_bounds__(256, 2) void decoder_kernel(
    const float* __restrict__ ctxv,    // [2,96,32768]
    const float* __restrict__ ctxvt,   // [2,32768,96] (in ws) or alias
    const float* __restrict__ qwc,     // [2,32768,3]
    const float* __restrict__ aff,     // [2,4,4]
    const float* __restrict__ b01, const float* __restrict__ b02,
    const float* __restrict__ b11, const float* __restrict__ b12,
    const float* __restrict__ bpost,
    const unsigned short* __restrict__ ws,
    float* __restrict__ out)           // [2,45,32768]
{
  __shared__ __align__(16) short sY[128 * ASTR];      // skip accumulator (bf16)
  __shared__ __align__(16) short sC[128 * CSTR];      // coord plane (bf16, 80 ch)
  __shared__ __align__(16) short sH[128 * ASTR];      // hidden (in-place) / pred f32
  __shared__ unsigned short sTs[2304];                // sincos table [16q][3d][2off][2sc][12fj]
  __shared__ float swtri[128];
  __shared__ int   sqbot[16][3];
  __shared__ float sqsub[16][3];
  // total ~79.2 KB -> 2 blocks/CU

  const int t = threadIdx.x;
  const int blk = blockIdx.x;
  const int b = blk >> 11;
  const int qbase = (blk & 2047) * 16;
  const int lane = t & 63, wid = t >> 6;
  const int ln15 = lane & 15, quad = lane >> 4;
  const int rowb = wid * 32;
  const float* badj = (const float*)(ws + 2 * TOTW);

  // ---- per-query setup (wave 0, 16 threads) ----
  if (t < 16) {
    float m[4][8];
    for (int i = 0; i < 4; ++i)
      for (int j = 0; j < 4; ++j) {
        m[i][j] = aff[b * 16 + i * 4 + j];
        m[i][j + 4] = (i == j) ? 1.f : 0.f;
      }
    for (int col = 0; col < 4; ++col) {
      int piv = col; float best = fabsf(m[col][col]);
      for (int rr = col + 1; rr < 4; ++rr) {
        float v = fabsf(m[rr][col]);
        if (v > best) { best = v; piv = rr; }
      }
      if (piv != col)
        for (int j = 0; j < 8; ++j) { float tmp = m[col][j]; m[col][j] = m[piv][j]; m[piv][j] = tmp; }
      float d = 1.f / m[col][col];
      for (int j = 0; j < 8; ++j) m[col][j] *= d;
      for (int rr = 0; rr < 4; ++rr) if (rr != col) {
        float f = m[rr][col];
        for (int j = 0; j < 8; ++j) m[rr][j] -= f * m[col][j];
      }
    }
    int qi = qbase + t;
    float x = qwc[((size_t)b * NQv + qi) * 3 + 0];
    float y = qwc[((size_t)b * NQv + qi) * 3 + 1];
    float z = qwc[((size_t)b * NQv + qi) * 3 + 2];
    float v0 = m[0][4] * x + m[0][5] * y + m[0][6] * z + m[0][7];
    float v1 = m[1][4] * x + m[1][5] * y + m[1][6] * z + m[1][7];
    float v2 = m[2][4] * x + m[2][5] * y + m[2][6] * z + m[2][7];
    int i0 = (int)floorf(v0), i1 = (int)floorf(v1), i2 = (int)floorf(v2);
    sqbot[t][0] = i0; sqbot[t][1] = i1; sqbot[t][2] = i2;
    sqsub[t][0] = v0 - (float)i0; sqsub[t][1] = v1 - (float)i1; sqsub[t][2] = v2 - (float)i2;
  }
  __syncthreads();

  // ---- block-wide sincos table build: 576 tasks = 16q x 3d x 12fj ----
#pragma unroll
  for (int i = 0; i < 3; ++i) {
    int u = t + 256 * i;
    if (u < 576) {
      int q = u / 36, rem = u - 36 * q, d = rem / 12, fj = rem - 12 * d;
      float sub = sqsub[q][d];
      float freq = exp2f((float)fj * 0.13208020839342968f);   // 3^(fj/12)
#pragma unroll
      for (int off = 0; off < 2; ++off) {
        float rel = (sub - (float)off + 1.f) * 0.5f;
        float ang = 6.283185307179586f * rel * freq;
        float sn, cs; __sincosf(ang, &sn, &cs);
        int base = ((q * 3 + d) * 2 + off) * 24 + fj;
        sTs[base]      = f2bfu(sn);   // sc=0 (sin)
        sTs[base + 12] = f2bfu(cs);   // sc=1 (cos)
      }
    }
  }
  __syncthreads();

  // ---- per-wave prologue: wtri + Y (feats) + COORD planes (rows rowb..rowb+31) ----
  if (lane < 32) {
    int row = rowb + lane;
    int q = row >> 3, cor = row & 7;
    int oi = (cor >> 2) & 1, oj = (cor >> 1) & 1, ok = cor & 1;
    float wx = oi ? sqsub[q][0] : 1.f - sqsub[q][0];
    float wy = oj ? sqsub[q][1] : 1.f - sqsub[q][1];
    float wz = ok ? sqsub[q][2] : 1.f - sqsub[q][2];
    swtri[row] = wx * wy * wz;
  }
  {
    const int row = rowb + (lane >> 1);
    const int q = row >> 3, cor = row & 7;
    const int oi = (cor >> 2) & 1, oj = (cor >> 1) & 1, ok = cor & 1;
    const int jb = (lane & 1) * 48;
    const int ix = clamp31(sqbot[q][0] + oi);
    const int iy = clamp31(sqbot[q][1] + oj);
    const int iz = clamp31(sqbot[q][2] + ok);
    const int spat = (ix << 10) | (iy << 5) | iz;
    // Y = feats
    if (TRANSPOSED) {
      const float* src = ctxvt + ((size_t)(b << 15) + spat) * 96 + jb;
#pragma unroll
      for (int g = 0; g < 12; ++g) {
        float4v v = *(const float4v*)(src + 4 * g);
        *(uint2*)&sY[row * ASTR + jb + 4 * g] = make_uint2(pkp(v[0], v[1]), pkp(v[2], v[3]));
      }
    } else {
#pragma unroll 4
      for (int g = 0; g < 12; ++g) {
        float vv[4];
#pragma unroll
        for (int r = 0; r < 4; ++r)
          vv[r] = ctxv[(((size_t)(b * 96 + jb + 4 * g + r)) << 15) + spat];
        *(uint2*)&sY[row * ASTR + jb + 4 * g] = make_uint2(pkp(vv[0], vv[1]), pkp(vv[2], vv[3]));
      }
    }
    // COORD plane (80 ch): [cw-15.5(3) qw-15.5(3) enc(72) pad(2)] from table
    int offv[3]; offv[0] = oi; offv[1] = oj; offv[2] = ok;
    const int cbase = (lane & 1) * 40;
    float qw3[3];
#pragma unroll
    for (int k = 0; k < 3; ++k) qw3[k] = qwc[((size_t)b * NQv + qbase + q) * 3 + k];
#pragma unroll
    for (int g = 0; g < 10; ++g) {
      unsigned short hv[4];
#pragma unroll
      for (int r = 0; r < 4; ++r) {
        int ch = cbase + 4 * g + r;
        if (ch < 3) {
          float v = (float)clamp31(sqbot[q][ch] + offv[ch]) - 15.5f;
          hv[r] = (unsigned short)(rnd16(v) >> 16);
        } else if (ch < 6) {
          float v = qw3[ch - 3] - 15.5f;
          hv[r] = (unsigned short)(rnd16(v) >> 16);
        } else if (ch < 78) {
          int i2 = ch - 6, d = i2 / 24, rr = i2 - 24 * d, sc = rr / 12, fj = rr - 12 * sc;
          hv[r] = sTs[(((q * 3 + d) * 2 + offv[d]) * 2 + sc) * 12 + fj];
        } else hv[r] = 0;
      }
      *(uint2*)&sC[row * CSTR + cbase + 4 * g] =
          make_uint2((unsigned int)hv[0] | ((unsigned int)hv[1] << 16),
                     (unsigned int)hv[2] | ((unsigned int)hv[3] << 16));
    }
  }
  // no barrier: planes are wave-local from here on

  auto epiH = [&](float4v (&C)[6][2]) {
#pragma unroll
    for (int mt = 0; mt < 6; ++mt)
#pragma unroll
      for (int nt = 0; nt < 2; ++nt) {
        int idx = (rowb + nt * 16 + ln15) * ASTR + mt * 16 + quad * 4;
        *(uint2*)&sH[idx] = make_uint2(pkp(silu_f(C[mt][nt][0]), silu_f(C[mt][nt][1])),
                                       pkp(silu_f(C[mt][nt][2]), silu_f(C[mt][nt][3])));
      }
  };
  auto epiSkip = [&](float4v (&C)[6][2]) {
#pragma unroll
    for (int mt = 0; mt < 6; ++mt)
#pragma unroll
      for (int nt = 0; nt < 2; ++nt) {
        int idx = (rowb + nt * 16 + ln15) * ASTR + mt * 16 + quad * 4;
        uint2 oh = *(uint2*)&sY[idx];
        float y0 = __uint_as_float(oh.x << 16)          + silu_f(C[mt][nt][0]);
        float y1 = __uint_as_float(oh.x & 0xffff0000u)  + silu_f(C[mt][nt][1]);
        float y2 = __uint_as_float(oh.y << 16)          + silu_f(C[mt][nt][2]);
        float y3 = __uint_as_float(oh.y & 0xffff0000u)  + silu_f(C[mt][nt][3]);
        *(uint2*)&sY[idx] = make_uint2(pkp(y0, y1), pkp(y2, y3));
      }
  };

  {
    float4v C[6][2];
    run_layer<6, 6, true >(ws + OW00, 192, sY, sC, badj,      96, C, lane, rowb);
    epiH(C);
    run_layer<6, 3, false>(ws + OW01, 96,  sH, sC, b01,       96, C, lane, rowb);
    epiH(C);
    run_layer<6, 3, false>(ws + OW02, 96,  sH, sC, b02,       96, C, lane, rowb);
    epiSkip(C);
    run_layer<6, 6, true >(ws + OW10, 192, sY, sC, badj + 96, 96, C, lane, rowb);
    epiH(C);
    run_layer<6, 3, false>(ws + OW11, 96,  sH, sC, b11,       96, C, lane, rowb);
    epiH(C);
    run_layer<6, 3, false>(ws + OW12, 96,  sH, sC, b12,       96, C, lane, rowb);
    epiSkip(C);
  }
  float* pred = (float*)sH;                 // [row][52] f32 view of sH rows
  {
    float4v Cp[3][2];
    run_layer<3, 3, false>(ws + OWPOST, 96, sY, sC, bpost, 45, Cp, lane, rowb);
#pragma unroll
    for (int mt = 0; mt < 3; ++mt)
#pragma unroll
      for (int nt = 0; nt < 2; ++nt) {
        int row = rowb + nt * 16 + ln15, c0 = mt * 16 + quad * 4;
        float w = swtri[row];
        float4v v = Cp[mt][nt];
        v[0] *= w; v[1] *= w; v[2] *= w; v[3] *= w;
        *(float4v*)&pred[row * 52 + c0] = v;
      }
  }
  // ---- per-wave trilinear combine (queries wid*4..wid*4+3) + store ----
#pragma unroll
  for (int i = 0; i < 3; ++i) {
    int u = lane + 64 * i;
    if (u < 180) {
      int ql = u / 45, ch = u - ql * 45;
      float s = 0.f;
#pragma unroll
      for (int cor = 0; cor < 8; ++cor) s += pred[(rowb + ql * 8 + cor) * 52 + ch];
      out[(((size_t)(b * 45 + ch)) << 15) + qbase + wid * 4 + ql] = s;
    }
  }
}

extern "C" void kernel_launch(void* const* d_in, const int* in_sizes, int n_in,
                              void* d_out, int out_size, void* d_ws, size_t ws_size,
                              hipStream_t stream) {
  (void)in_sizes; (void)n_in; (void)out_size;
  const float* ctxv  = (const float*)d_in[0];
  const float* qwc   = (const float*)d_in[2];
  const float* aff   = (const float*)d_in[4];
  const float* w00   = (const float*)d_in[8];
  const float* b00   = (const float*)d_in[9];
  const float* w01   = (const float*)d_in[10];
  const float* b01   = (const float*)d_in[11];
  const float* w02   = (const float*)d_in[12];
  const float* b02   = (const float*)d_in[13];
  const float* w10   = (const float*)d_in[14];
  const float* b10   = (const float*)d_in[15];
  const float* w11   = (const float*)d_in[16];
  const float* b11   = (const float*)d_in[17];
  const float* w12   = (const float*)d_in[18];
  const float* b12   = (const float*)d_in[19];
  const float* wpost = (const float*)d_in[20];
  const float* bpost = (const float*)d_in[21];
  unsigned short* ws = (unsigned short*)d_ws;
  float* out = (float*)d_out;

  const size_t wbytes = (size_t)TOTW * 2 * sizeof(unsigned short) + 768;
  const size_t tbytes = (size_t)2 * 32768 * 96 * sizeof(float);
  float* ctxvt = (float*)((char*)d_ws + wbytes);
  const bool useT = ws_size >= wbytes + tbytes;

  convert_weights<<<dim3((TOTW + 192 + 255) / 256), dim3(256), 0, stream>>>(
      w00, w01, w02, w10, w11, w12, wpost, b00, b10, ws);
  if (useT) {
    transpose_ctxv<<<dim3(1024), dim3(256), 0, stream>>>(ctxv, ctxvt);
    decoder_kernel<true><<<dim3(4096), dim3(256), 0, stream>>>(
        ctxv, ctxvt, qwc, aff, b01, b02, b11, b12, bpost, ws, out);
  } else {
    decoder_kernel<false><<<dim3(4096), dim3(256), 0, stream>>>(
        ctxv, ctxv, qwc, aff, b01, b02, b11, b12, bpost, ws, out);
  }
}

// Round 18
// 369.988 us; speedup vs baseline: 1.5746x; 1.0406x over previous
//
#include <hip/hip_runtime.h>

#define NQv   32768
#define TOTW  78336
#define OW00  0
#define OW01  18432
#define OW02  27648
#define OW10  36864
#define OW11  55296
#define OW12  64512
#define OWPOST 73728
#define ASTR  104     // feats/hidden plane stride in shorts (208B = 13*16B)
#define CSTR  80      // coord plane stride in shorts (160B, 16B-aligned)
#define WBLK  307     // pre-kernel blocks for the weight path

typedef __attribute__((ext_vector_type(8))) short  short8;
typedef __attribute__((ext_vector_type(4))) float  float4v;

__device__ __forceinline__ float bfu2f(unsigned short u) {
  return __uint_as_float(((unsigned int)u) << 16);
}
__device__ __forceinline__ unsigned short f2bfu(float f) {
  unsigned int x = __float_as_uint(f);
  x += 0x7fffu + ((x >> 16) & 1u);   // RNE
  return (unsigned short)(x >> 16);
}
// ties-away bf16 round, result in bits [31:16]
__device__ __forceinline__ unsigned int rnd16(float f) {
  return __float_as_uint(f) + 0x8000u;
}
// pack two floats -> (bf16(hi)<<16)|bf16(lo) in 3 VALU
__device__ __forceinline__ unsigned int pkp(float lo, float hi) {
  return __builtin_amdgcn_perm(rnd16(hi), rnd16(lo), 0x07060302u);
}
// silu via HW reciprocal (v_rcp_f32, ~1 ulp) instead of the ~10-instr f32 divide
__device__ __forceinline__ float silu_f(float x) {
  float e = __expf(-x);
  return x * __builtin_amdgcn_rcpf(1.f + e);
}
__device__ __forceinline__ int clamp31(int v) { return min(max(v, 0), 31); }

// ---- fused pre-kernel: blocks [0,WBLK) convert weights; [WBLK, WBLK+1024) transpose ctxv ----
// weights -> bf16 hi/lo [n][kpad] + centered-coord adjusted biases (f32)
// ctxv [b][c][spat] f32 -> ctxvt [b][spat][c] bf16
__global__ __launch_bounds__(256) void prep_kernel(
    const float* __restrict__ ctxv,
    const float* __restrict__ w00, const float* __restrict__ w01,
    const float* __restrict__ w02, const float* __restrict__ w10,
    const float* __restrict__ w11, const float* __restrict__ w12,
    const float* __restrict__ wpost,
    const float* __restrict__ b00, const float* __restrict__ b10,
    unsigned short* __restrict__ ws, unsigned short* __restrict__ ctxvt)
{
  __shared__ float tile[96][65];
  const int blk0 = blockIdx.x;
  const int t = threadIdx.x;
  if (blk0 < WBLK) {
    int e = blk0 * 256 + t;
    if (e >= TOTW + 192) return;
    if (e >= TOTW) {
      // b' = b + 15.5*sum_{k=96..101} W[k][ch]  (coords centered by 15.5)
      int e2 = e - TOTW, mat = e2 / 96, ch = e2 - mat * 96;
      const float* w = mat ? w10 : w00;
      const float* bb = mat ? b10 : b00;
      float s = bb[ch];
#pragma unroll
      for (int k = 0; k < 6; ++k) s += 15.5f * w[(96 + k) * 96 + ch];
      ((float*)(ws + 2 * TOTW))[e2] = s;
      return;
    }
    int base, kpad, Ksrc, Nsrc; const float* src;
    if      (e < OW01)  { base = OW00;  kpad = 192; Ksrc = 174; Nsrc = 96; src = w00; }
    else if (e < OW02)  { base = OW01;  kpad = 96;  Ksrc = 96;  Nsrc = 96; src = w01; }
    else if (e < OW10)  { base = OW02;  kpad = 96;  Ksrc = 96;  Nsrc = 96; src = w02; }
    else if (e < OW11)  { base = OW10;  kpad = 192; Ksrc = 174; Nsrc = 96; src = w10; }
    else if (e < OW12)  { base = OW11;  kpad = 96;  Ksrc = 96;  Nsrc = 96; src = w11; }
    else if (e < OWPOST){ base = OW12;  kpad = 96;  Ksrc = 96;  Nsrc = 96; src = w12; }
    else                { base = OWPOST;kpad = 96;  Ksrc = 96;  Nsrc = 45; src = wpost; }
    int local = e - base;
    int n = local / kpad, k = local - n * kpad;
    float v = (k < Ksrc && n < Nsrc) ? src[k * Nsrc + n] : 0.f;
    unsigned short hi = f2bfu(v);
    ws[e]        = hi;
    ws[e + TOTW] = f2bfu(v - bfu2f(hi));
    return;
  }
  const int blk = blk0 - WBLK;              // 1024 = 2 batches * 512
  const int b = blk >> 9, s0 = (blk & 511) << 6;
  const int cq = t >> 6, sl = t & 63;
#pragma unroll
  for (int p = 0; p < 24; ++p) {
    int c = cq + p * 4;
    tile[c][sl] = ctxv[(((size_t)(b * 96 + c)) << 15) + s0 + sl];
  }
  __syncthreads();
#pragma unroll
  for (int i = 0; i < 24; ++i) {
    int u = t + 256 * i;
    int s = u / 96, c = u - s * 96;
    ctxvt[((size_t)(b << 15) + s0 + s) * 96 + c] = f2bfu(tile[c][s]);
  }
}

// ---- layer GEMM: hi-only weights from global (L2-hot, depth-3 prefetch);
//      acts bf16 in LDS with depth-2 B-fragment prefetch ----
// COORD layers: chunks 0..2 from pA (stride ASTR), chunks 3..5 from pC (stride CSTR);
// chunk 5 quads 2..3 are structurally zero channels -> zero B-fragment.
// NOTE: W refill must stay AFTER the MFMA block — (cb+3)%3 == cb%3 aliases the
// buffer currently being read (round-17 bug).
template<int NM, int NC, bool COORD>
__device__ __forceinline__ void run_layer(
    const unsigned short* __restrict__ wmat, int kpad,
    const short* pA, const short* pC,
    const float* __restrict__ bias, int biasN,
    float4v (&C)[NM][2], int lane, int rowb)
{
  const int ln15 = lane & 15, quad = lane >> 4;
  if (biasN >= NM * 16) {
#pragma unroll
    for (int mt = 0; mt < NM; ++mt) {
      float4v bv = *(const float4v*)(bias + mt * 16 + quad * 4);
      C[mt][0] = bv; C[mt][1] = bv;
    }
  } else {
#pragma unroll
    for (int mt = 0; mt < NM; ++mt) {
      int c0 = mt * 16 + quad * 4;
      float4v bv;
#pragma unroll
      for (int r = 0; r < 4; ++r) bv[r] = (c0 + r < biasN) ? bias[c0 + r] : 0.f;
      C[mt][0] = bv; C[mt][1] = bv;
    }
  }
  short8 Wh[3][NM];                       // depth-3 rotating weight buffer
  short8 Bh[2][2];                        // depth-2 B-fragment buffer
  auto loadW = [&](int cb, int buf) {
#pragma unroll
    for (int mt = 0; mt < NM; ++mt)
      Wh[buf][mt] = *(const short8*)(wmat + (mt * 16 + ln15) * kpad + cb * 32 + quad * 8);
  };
  auto loadB = [&](int cb, int buf) {
    if (COORD && cb >= 3) {
      const int kofs = (cb - 3) * 32;
#pragma unroll
      for (int nt = 0; nt < 2; ++nt) {
        if (cb == 5 && quad >= 2) {
          Bh[buf][nt] = (short8)0;        // channels 80..95 are zero
        } else {
          Bh[buf][nt] = *(const short8*)&pC[(rowb + nt * 16 + ln15) * CSTR + kofs + quad * 8];
        }
      }
    } else {
      const int kofs = cb * 32;
#pragma unroll
      for (int nt = 0; nt < 2; ++nt)
        Bh[buf][nt] = *(const short8*)&pA[(rowb + nt * 16 + ln15) * ASTR + kofs + quad * 8];
    }
  };
  loadW(0, 0);
  if (NC > 1) loadW(1, 1);
  if (NC > 2) loadW(2, 2);
  loadB(0, 0);
#pragma unroll
  for (int cb = 0; cb < NC; ++cb) {
    const int cur = cb & 1;
    const int wcur = cb % 3;
    if (cb + 1 < NC) loadB(cb + 1, cur ^ 1);   // B for next chunk in flight over MFMAs
#pragma unroll
    for (int mt = 0; mt < NM; ++mt)
#pragma unroll
      for (int nt = 0; nt < 2; ++nt)
        C[mt][nt] = __builtin_amdgcn_mfma_f32_16x16x32_bf16(Wh[wcur][mt], Bh[cur][nt], C[mt][nt], 0, 0, 0);
    if (cb + 3 < NC) loadW(cb + 3, wcur);      // refill AFTER use (buffer aliases)
  }
}

template<bool TRANSPOSED>
__global__ __launch_bounds__(256, 2) void decoder_kernel(
    const float* __restrict__ ctxv,            // [2,96,32768] f32
    const unsigned short* __restrict__ ctxvt,  // [2,32768,96] bf16 (in ws) or unused
    const float* __restrict__ qwc,     // [2,32768,3]
    const float* __restrict__ aff,     // [2,4,4]
    const float* __restrict__ b01, const float* __restrict__ b02,
    const float* __restrict__ b11, const float* __restrict__ b12,
    const float* __restrict__ bpost,
    const unsigned short* __restrict__ ws,
    float* __restrict__ out)           // [2,45,32768]
{
  __shared__ __align__(16) short sY[128 * ASTR];      // skip accumulator (bf16)
  __shared__ __align__(16) short sC[128 * CSTR];      // coord plane (bf16, 80 ch)
  __shared__ __align__(16) short sH[128 * ASTR];      // hidden (in-place) / pred f32
  __shared__ unsigned short sTs[2304];                // sincos table [16q][3d][2off][2sc][12fj]
  __shared__ float swtri[128];
  __shared__ int   sqbot[16][3];
  __shared__ float sqsub[16][3];
  // total ~79.2 KB -> 2 blocks/CU

  const int t = threadIdx.x;
  const int blk = blockIdx.x;
  const int b = blk >> 11;
  const int qbase = (blk & 2047) * 16;
  const int lane = t & 63, wid = t >> 6;
  const int ln15 = lane & 15, quad = lane >> 4;
  const int rowb = wid * 32;
  const float* badj = (const float*)(ws + 2 * TOTW);

  // ---- per-query setup (wave 0, 16 threads) ----
  if (t < 16) {
    float m[4][8];
    for (int i = 0; i < 4; ++i)
      for (int j = 0; j < 4; ++j) {
        m[i][j] = aff[b * 16 + i * 4 + j];
        m[i][j + 4] = (i == j) ? 1.f : 0.f;
      }
    for (int col = 0; col < 4; ++col) {
      int piv = col; float best = fabsf(m[col][col]);
      for (int rr = col + 1; rr < 4; ++rr) {
        float v = fabsf(m[rr][col]);
        if (v > best) { best = v; piv = rr; }
      }
      if (piv != col)
        for (int j = 0; j < 8; ++j) { float tmp = m[col][j]; m[col][j] = m[piv][j]; m[piv][j] = tmp; }
      float d = 1.f / m[col][col];
      for (int j = 0; j < 8; ++j) m[col][j] *= d;
      for (int rr = 0; rr < 4; ++rr) if (rr != col) {
        float f = m[rr][col];
        for (int j = 0; j < 8; ++j) m[rr][j] -= f * m[col][j];
      }
    }
    int qi = qbase + t;
    float x = qwc[((size_t)b * NQv + qi) * 3 + 0];
    float y = qwc[((size_t)b * NQv + qi) * 3 + 1];
    float z = qwc[((size_t)b * NQv + qi) * 3 + 2];
    float v0 = m[0][4] * x + m[0][5] * y + m[0][6] * z + m[0][7];
    float v1 = m[1][4] * x + m[1][5] * y + m[1][6] * z + m[1][7];
    float v2 = m[2][4] * x + m[2][5] * y + m[2][6] * z + m[2][7];
    int i0 = (int)floorf(v0), i1 = (int)floorf(v1), i2 = (int)floorf(v2);
    sqbot[t][0] = i0; sqbot[t][1] = i1; sqbot[t][2] = i2;
    sqsub[t][0] = v0 - (float)i0; sqsub[t][1] = v1 - (float)i1; sqsub[t][2] = v2 - (float)i2;
  }
  __syncthreads();

  // ---- block-wide sincos table build: 576 tasks = 16q x 3d x 12fj ----
#pragma unroll
  for (int i = 0; i < 3; ++i) {
    int u = t + 256 * i;
    if (u < 576) {
      int q = u / 36, rem = u - 36 * q, d = rem / 12, fj = rem - 12 * d;
      float sub = sqsub[q][d];
      float freq = exp2f((float)fj * 0.13208020839342968f);   // 3^(fj/12)
#pragma unroll
      for (int off = 0; off < 2; ++off) {
        float rel = (sub - (float)off + 1.f) * 0.5f;
        float ang = 6.283185307179586f * rel * freq;
        float sn, cs; __sincosf(ang, &sn, &cs);
        int base = ((q * 3 + d) * 2 + off) * 24 + fj;
        sTs[base]      = f2bfu(sn);   // sc=0 (sin)
        sTs[base + 12] = f2bfu(cs);   // sc=1 (cos)
      }
    }
  }
  __syncthreads();

  // ---- per-wave prologue: wtri + Y (feats) + COORD planes (rows rowb..rowb+31) ----
  if (lane < 32) {
    int row = rowb + lane;
    int q = row >> 3, cor = row & 7;
    int oi = (cor >> 2) & 1, oj = (cor >> 1) & 1, ok = cor & 1;
    float wx = oi ? sqsub[q][0] : 1.f - sqsub[q][0];
    float wy = oj ? sqsub[q][1] : 1.f - sqsub[q][1];
    float wz = ok ? sqsub[q][2] : 1.f - sqsub[q][2];
    swtri[row] = wx * wy * wz;
  }
  {
    const int row = rowb + (lane >> 1);
    const int q = row >> 3, cor = row & 7;
    const int oi = (cor >> 2) & 1, oj = (cor >> 1) & 1, ok = cor & 1;
    const int jb = (lane & 1) * 48;
    const int ix = clamp31(sqbot[q][0] + oi);
    const int iy = clamp31(sqbot[q][1] + oj);
    const int iz = clamp31(sqbot[q][2] + ok);
    const int spat = (ix << 10) | (iy << 5) | iz;
    // Y = feats
    if (TRANSPOSED) {
      const unsigned short* src = ctxvt + ((size_t)(b << 15) + spat) * 96 + jb;
#pragma unroll
      for (int g = 0; g < 6; ++g)
        *(short8*)&sY[row * ASTR + jb + 8 * g] = *(const short8*)(src + 8 * g);
    } else {
#pragma unroll 4
      for (int g = 0; g < 12; ++g) {
        float vv[4];
#pragma unroll
        for (int r = 0; r < 4; ++r)
          vv[r] = ctxv[(((size_t)(b * 96 + jb + 4 * g + r)) << 15) + spat];
        *(uint2*)&sY[row * ASTR + jb + 4 * g] = make_uint2(pkp(vv[0], vv[1]), pkp(vv[2], vv[3]));
      }
    }
    // COORD plane (80 ch): [cw-15.5(3) qw-15.5(3) enc(72) pad(2)] from table
    int offv[3]; offv[0] = oi; offv[1] = oj; offv[2] = ok;
    const int cbase = (lane & 1) * 40;
    float qw3[3];
#pragma unroll
    for (int k = 0; k < 3; ++k) qw3[k] = qwc[((size_t)b * NQv + qbase + q) * 3 + k];
#pragma unroll
    for (int g = 0; g < 10; ++g) {
      unsigned short hv[4];
#pragma unroll
      for (int r = 0; r < 4; ++r) {
        int ch = cbase + 4 * g + r;
        if (ch < 3) {
          float v = (float)clamp31(sqbot[q][ch] + offv[ch]) - 15.5f;
          hv[r] = (unsigned short)(rnd16(v) >> 16);
        } else if (ch < 6) {
          float v = qw3[ch - 3] - 15.5f;
          hv[r] = (unsigned short)(rnd16(v) >> 16);
        } else if (ch < 78) {
          int i2 = ch - 6, d = i2 / 24, rr = i2 - 24 * d, sc = rr / 12, fj = rr - 12 * sc;
          hv[r] = sTs[(((q * 3 + d) * 2 + offv[d]) * 2 + sc) * 12 + fj];
        } else hv[r] = 0;
      }
      *(uint2*)&sC[row * CSTR + cbase + 4 * g] =
          make_uint2((unsigned int)hv[0] | ((unsigned int)hv[1] << 16),
                     (unsigned int)hv[2] | ((unsigned int)hv[3] << 16));
    }
  }
  // no barrier: planes are wave-local from here on

  auto epiH = [&](float4v (&C)[6][2]) {
#pragma unroll
    for (int mt = 0; mt < 6; ++mt)
#pragma unroll
      for (int nt = 0; nt < 2; ++nt) {
        int idx = (rowb + nt * 16 + ln15) * ASTR + mt * 16 + quad * 4;
        *(uint2*)&sH[idx] = make_uint2(pkp(silu_f(C[mt][nt][0]), silu_f(C[mt][nt][1])),
                                       pkp(silu_f(C[mt][nt][2]), silu_f(C[mt][nt][3])));
      }
  };
  auto epiSkip = [&](float4v (&C)[6][2]) {
#pragma unroll
    for (int mt = 0; mt < 6; ++mt)
#pragma unroll
      for (int nt = 0; nt < 2; ++nt) {
        int idx = (rowb + nt * 16 + ln15) * ASTR + mt * 16 + quad * 4;
        uint2 oh = *(uint2*)&sY[idx];
        float y0 = __uint_as_float(oh.x << 16)          + silu_f(C[mt][nt][0]);
        float y1 = __uint_as_float(oh.x & 0xffff0000u)  + silu_f(C[mt][nt][1]);
        float y2 = __uint_as_float(oh.y << 16)          + silu_f(C[mt][nt][2]);
        float y3 = __uint_as_float(oh.y & 0xffff0000u)  + silu_f(C[mt][nt][3]);
        *(uint2*)&sY[idx] = make_uint2(pkp(y0, y1), pkp(y2, y3));
      }
  };

  {
    float4v C[6][2];
    run_layer<6, 6, true >(ws + OW00, 192, sY, sC, badj,      96, C, lane, rowb);
    epiH(C);
    run_layer<6, 3, false>(ws + OW01, 96,  sH, sC, b01,       96, C, lane, rowb);
    epiH(C);
    run_layer<6, 3, false>(ws + OW02, 96,  sH, sC, b02,       96, C, lane, rowb);
    epiSkip(C);
    run_layer<6, 6, true >(ws + OW10, 192, sY, sC, badj + 96, 96, C, lane, rowb);
    epiH(C);
    run_layer<6, 3, false>(ws + OW11, 96,  sH, sC, b11,       96, C, lane, rowb);
    epiH(C);
    run_layer<6, 3, false>(ws + OW12, 96,  sH, sC, b12,       96, C, lane, rowb);
    epiSkip(C);
  }
  float* pred = (float*)sH;                 // [row][52] f32 view of sH rows
  {
    float4v Cp[3][2];
    run_layer<3, 3, false>(ws + OWPOST, 96, sY, sC, bpost, 45, Cp, lane, rowb);
#pragma unroll
    for (int mt = 0; mt < 3; ++mt)
#pragma unroll
      for (int nt = 0; nt < 2; ++nt) {
        int row = rowb + nt * 16 + ln15, c0 = mt * 16 + quad * 4;
        float w = swtri[row];
        float4v v = Cp[mt][nt];
        v[0] *= w; v[1] *= w; v[2] *= w; v[3] *= w;
        *(float4v*)&pred[row * 52 + c0] = v;
      }
  }
  // ---- per-wave trilinear combine (queries wid*4..wid*4+3) + store ----
#pragma unroll
  for (int i = 0; i < 3; ++i) {
    int u = lane + 64 * i;
    if (u < 180) {
      int ql = u / 45, ch = u - ql * 45;
      float s = 0.f;
#pragma unroll
      for (int cor = 0; cor < 8; ++cor) s += pred[(rowb + ql * 8 + cor) * 52 + ch];
      out[(((size_t)(b * 45 + ch)) << 15) + qbase + wid * 4 + ql] = s;
    }
  }
}

extern "C" void kernel_launch(void* const* d_in, const int* in_sizes, int n_in,
                              void* d_out, int out_size, void* d_ws, size_t ws_size,
                              hipStream_t stream) {
  (void)in_sizes; (void)n_in; (void)out_size;
  const float* ctxv  = (const float*)d_in[0];
  const float* qwc   = (const float*)d_in[2];
  const float* aff   = (const float*)d_in[4];
  const float* w00   = (const float*)d_in[8];
  const float* b00   = (const float*)d_in[9];
  const float* w01   = (const float*)d_in[10];
  const float* b01   = (const float*)d_in[11];
  const float* w02   = (const float*)d_in[12];
  const float* b02   = (const float*)d_in[13];
  const float* w10   = (const float*)d_in[14];
  const float* b10   = (const float*)d_in[15];
  const float* w11   = (const float*)d_in[16];
  const float* b11   = (const float*)d_in[17];
  const float* w12   = (const float*)d_in[18];
  const float* b12   = (const float*)d_in[19];
  const float* wpost = (const float*)d_in[20];
  const float* bpost = (const float*)d_in[21];
  unsigned short* ws = (unsigned short*)d_ws;
  float* out = (float*)d_out;

  const size_t wbytes = (size_t)TOTW * 2 * sizeof(unsigned short) + 768;  // hi+lo + badj
  const size_t tbytes = (size_t)2 * 32768 * 96 * sizeof(unsigned short);  // bf16 ctxvt
  unsigned short* ctxvt = (unsigned short*)((char*)d_ws + wbytes);
  const bool useT = ws_size >= wbytes + tbytes;

  if (useT) {
    prep_kernel<<<dim3(WBLK + 1024), dim3(256), 0, stream>>>(
        ctxv, w00, w01, w02, w10, w11, w12, wpost, b00, b10, ws, ctxvt);
    decoder_kernel<true><<<dim3(4096), dim3(256), 0, stream>>>(
        ctxv, ctxvt, qwc, aff, b01, b02, b11, b12, bpost, ws, out);
  } else {
    prep_kernel<<<dim3(WBLK), dim3(256), 0, stream>>>(
        ctxv, w00, w01, w02, w10, w11, w12, wpost, b00, b10, ws, ctxvt);
    decoder_kernel<false><<<dim3(4096), dim3(256), 0, stream>>>(
        ctxv, ctxvt, qwc, aff, b01, b02, b11, b12, bpost, ws, out);
  }
}